// Round 5
// baseline (299.142 us; speedup 1.0000x reference)
//
#include <hip/hip_runtime.h>
#include <hip/hip_bf16.h>
#include <math.h>

// Problem constants
#define S_  512
#define D_  2048
#define HK_ 8
#define HV_ 16
#define DK_ 128
#define DV_ 128
#define KEY_DIM_ 1024
#define VAL_DIM_ 2048
#define QKVZ_N  6144
#define EPS_ 1e-6f

typedef __attribute__((ext_vector_type(8))) short short8;
typedef __attribute__((ext_vector_type(4))) float f32x4;
typedef __attribute__((ext_vector_type(2))) float v2f;   // -> v_pk_* f32 ops
typedef unsigned short ushort_t;
typedef unsigned int uint_t;

// ---------------------------------------------------------------------------
// helpers
// ---------------------------------------------------------------------------
__device__ __forceinline__ ushort_t f2bf(float x) {
    uint_t u = __float_as_uint(x);
    return (ushort_t)((u + 0x7FFFu + ((u >> 16) & 1u)) >> 16);
}

// async global->LDS, 16B per lane; dest = lds_base + lane*16 (wave-uniform base)
__device__ __forceinline__ void gl2lds16(const void* g, void* l) {
    __builtin_amdgcn_global_load_lds((const __attribute__((address_space(1))) uint_t*)g,
                                     (__attribute__((address_space(3))) uint_t*)l, 16, 0, 0);
}
// async global->LDS, 4B per lane; dest = lds_base + lane*4
__device__ __forceinline__ void gl2lds4(const void* g, void* l) {
    __builtin_amdgcn_global_load_lds((const __attribute__((address_space(1))) uint_t*)g,
                                     (__attribute__((address_space(3))) uint_t*)l, 4, 0, 0);
}

// ---------------------------------------------------------------------------
// fp32 -> bf16 (flat)
// ---------------------------------------------------------------------------
__global__ __launch_bounds__(256) void convert_bf16(const float* __restrict__ X,
                                                    ushort_t* __restrict__ H, int n4) {
    int i = blockIdx.x * blockDim.x + threadIdx.x;
    if (i >= n4) return;
    float4 v = ((const float4*)X)[i];
    ushort4 h;
    h.x = f2bf(v.x); h.y = f2bf(v.y); h.z = f2bf(v.z); h.w = f2bf(v.w);
    ((ushort4*)H)[i] = h;
}

// ---------------------------------------------------------------------------
// W[K][N] fp32 -> T[N][K] bf16 (transpose + convert); grid (N/64, K/64), 256 thr
// ---------------------------------------------------------------------------
__global__ __launch_bounds__(256) void transpose_convert(const float* __restrict__ W,
                                                         ushort_t* __restrict__ Th,
                                                         int K, int N) {
    __shared__ float tile[64][65];
    const int kb = blockIdx.y * 64, nb = blockIdx.x * 64;
    const int t = threadIdx.x;
#pragma unroll
    for (int i = 0; i < 4; ++i) {
        int r = (t >> 4) + i * 16;
        int c4 = (t & 15) * 4;
        float4 v = *(const float4*)&W[(size_t)(kb + r) * N + nb + c4];
        tile[r][c4 + 0] = v.x; tile[r][c4 + 1] = v.y;
        tile[r][c4 + 2] = v.z; tile[r][c4 + 3] = v.w;
    }
    __syncthreads();
#pragma unroll
    for (int i = 0; i < 4; ++i) {
        int idx = t + 256 * i;
        int n = idx >> 4;
        int k4 = (idx & 15) * 4;
        ushort4 h;
        h.x = f2bf(tile[k4 + 0][n]); h.y = f2bf(tile[k4 + 1][n]);
        h.z = f2bf(tile[k4 + 2][n]); h.w = f2bf(tile[k4 + 3][n]);
        *(ushort4*)&Th[(size_t)(nb + n) * K + kb + k4] = h;
    }
}

// ---------------------------------------------------------------------------
// bf16 MFMA GEMM, m97 structure: C[M][N] fp32 = A[M][K] @ B^T (B given [N][K]).
// BK=64, double-buffered LDS, global_load_lds(16B) staging, prefetch-1.
// ---------------------------------------------------------------------------
template<int BM, int BN, int WR, int WC>
__global__ __launch_bounds__(256) void gemm_bf16(const ushort_t* __restrict__ A,
                                                 const ushort_t* __restrict__ B,
                                                 float* __restrict__ C,
                                                 int M, int N, int K) {
    constexpr int TM = BM / (16 * WR);
    constexpr int TN = BN / (16 * WC);
    constexpr int AI = (BM / 16) * 2;
    constexpr int BI = (BN / 16) * 2;

    __shared__ __align__(16) ushort_t sA[2][2][BM][32];
    __shared__ __align__(16) ushort_t sB[2][2][BN][32];

    const int t = threadIdx.x;
    const int w = t >> 6, lane = t & 63;
    const int wr = w / WC, wc = w % WC;
    const int lm = lane & 15, quad = lane >> 4;
    const int m0 = blockIdx.y * BM, n0 = blockIdx.x * BN;
    const int lrow = lane >> 2;
    const int lch  = (lane & 3) * 8;

    auto stage = [&](int buf, int k0) {
#pragma unroll
        for (int j = w; j < AI; j += 4) {
            int ks = j & 1, r0 = (j >> 1) * 16;
            gl2lds16(&A[(size_t)(m0 + r0 + lrow) * K + k0 + ks * 32 + lch],
                     &sA[buf][ks][r0][0]);
        }
#pragma unroll
        for (int j = w; j < BI; j += 4) {
            int ks = j & 1, r0 = (j >> 1) * 16;
            gl2lds16(&B[(size_t)(n0 + r0 + lrow) * K + k0 + ks * 32 + lch],
                     &sB[buf][ks][r0][0]);
        }
    };

    f32x4 acc[TM][TN] = {};
    stage(0, 0);
    __syncthreads();

    const int NK = K / 64;
    for (int it = 0; it < NK; ++it) {
        int buf = it & 1;
        if (it + 1 < NK) stage(buf ^ 1, (it + 1) * 64);
#pragma unroll
        for (int ks = 0; ks < 2; ++ks) {
            short8 bf[TN];
#pragma unroll
            for (int ni = 0; ni < TN; ++ni)
                bf[ni] = *(const short8*)&sB[buf][ks][wc * (TN * 16) + ni * 16 + lm][quad * 8];
#pragma unroll
            for (int mi = 0; mi < TM; ++mi) {
                short8 af = *(const short8*)&sA[buf][ks][wr * (TM * 16) + mi * 16 + lm][quad * 8];
#pragma unroll
                for (int ni = 0; ni < TN; ++ni)
                    acc[mi][ni] = __builtin_amdgcn_mfma_f32_16x16x32_bf16(af, bf[ni], acc[mi][ni], 0, 0, 0);
            }
        }
        __syncthreads();
    }

#pragma unroll
    for (int mi = 0; mi < TM; ++mi)
#pragma unroll
        for (int ni = 0; ni < TN; ++ni) {
            int row = m0 + wr * TM * 16 + mi * 16 + quad * 4;
            int col = n0 + wc * TN * 16 + ni * 16 + lm;
#pragma unroll
            for (int r = 0; r < 4; ++r)
                C[(size_t)(row + r) * N + col] = acc[mi][ni][r];
        }
}

// ---------------------------------------------------------------------------
// ba = hidden @ W_ba  (512x2048 @ 2048x32). One block per row s.
// ---------------------------------------------------------------------------
__global__ __launch_bounds__(256) void ba_kernel(const float* __restrict__ hid,
                                                 const float* __restrict__ Wba,
                                                 float* __restrict__ ba) {
    const int s = blockIdx.x;
    const int j = threadIdx.x & 31;
    const int kg = threadIdx.x >> 5;
    const float* h = hid + (size_t)s * D_;
    float sum = 0.f;
    const int k0 = kg * 256;
#pragma unroll 8
    for (int k = k0; k < k0 + 256; ++k)
        sum = fmaf(h[k], Wba[(size_t)k * 32 + j], sum);
    __shared__ float red[8][32];
    red[kg][j] = sum;
    __syncthreads();
    if (threadIdx.x < 32) {
        float tot = 0.f;
#pragma unroll
        for (int r = 0; r < 8; ++r) tot += red[r][j];
        ba[s * 32 + j] = tot;
    }
}

// ---------------------------------------------------------------------------
// causal depthwise conv (K=4) + silu + l2norm (q/k). grid (S,32), block 128.
// ---------------------------------------------------------------------------
__global__ __launch_bounds__(128) void conv_kernel(const float* __restrict__ qkvz,
                                                   const float* __restrict__ conv_w,
                                                   float* __restrict__ qc,
                                                   float* __restrict__ kc,
                                                   float* __restrict__ vc) {
    const int s   = blockIdx.x;
    const int grp = blockIdx.y;
    const int d   = threadIdx.x;

    int col, c;
    if (grp < 8) {
        int hk = grp;
        col = hk * 768 + d;
        c   = hk * 128 + d;
    } else if (grp < 16) {
        int hk = grp - 8;
        col = hk * 768 + 128 + d;
        c   = 1024 + (hk * 128 + d);
    } else {
        int hv = grp - 16;
        col = (hv >> 1) * 768 + 256 + (hv & 1) * 128 + d;
        c   = 2048 + (hv * 128 + d);
    }

    const float w0 = conv_w[c * 4 + 0];
    const float w1 = conv_w[c * 4 + 1];
    const float w2 = conv_w[c * 4 + 2];
    const float w3 = conv_w[c * 4 + 3];

    float x = 0.f;
    if (s - 3 >= 0) x += qkvz[(size_t)(s - 3) * QKVZ_N + col] * w0;
    if (s - 2 >= 0) x += qkvz[(size_t)(s - 2) * QKVZ_N + col] * w1;
    if (s - 1 >= 0) x += qkvz[(size_t)(s - 1) * QKVZ_N + col] * w2;
    x += qkvz[(size_t)s * QKVZ_N + col] * w3;

    x = x / (1.f + expf(-x));

    if (grp < 16) {
        float ss = x * x;
#pragma unroll
        for (int m = 1; m < 64; m <<= 1) ss += __shfl_xor(ss, m);
        __shared__ float red[2];
        int wid = threadIdx.x >> 6;
        if ((threadIdx.x & 63) == 0) red[wid] = ss;
        __syncthreads();
        float tot = red[0] + red[1];
        float scale = rsqrtf(tot + EPS_);
        if (grp < 8) {
            x = x * scale * 0.08838834764831845f;   // * DK^-0.5
            qc[((size_t)s * HK_ + grp) * DK_ + d] = x;
        } else {
            x = x * scale;
            kc[((size_t)s * HK_ + (grp - 8)) * DK_ + d] = x;
        }
    } else {
        vc[((size_t)s * HV_ + (grp - 16)) * DV_ + d] = x;
    }
}

// ---------------------------------------------------------------------------
// cross-lane reductions (pure DPP, no LDS traffic)
// ---------------------------------------------------------------------------
template<int CTRL>
__device__ __forceinline__ float dpp_xor(float x) {
    int v = __builtin_amdgcn_update_dpp(0, __float_as_int(x), CTRL, 0xF, 0xF, true);
    return __int_as_float(v);
}
__device__ __forceinline__ float red16(float x) {
    x += dpp_xor<0xB1>(x);   // xor 1
    x += dpp_xor<0x4E>(x);   // xor 2
    x += dpp_xor<0x141>(x);  // xor 4 (row_half_mirror)
    x += dpp_xor<0x140>(x);  // xor 8 (row_mirror)
    return x;
}
__device__ __forceinline__ float red32(float x) {
    x = red16(x);
    x += __int_as_float(__builtin_amdgcn_ds_swizzle(__float_as_int(x), 0x401F)); // xor 16
    return x;
}

// ---------------------------------------------------------------------------
// scal_kernel (gating fused): per (t,h) scalars {P, W1, beta, g}:
//   beta = sigmoid(b); g = exp(-exp(A_log)*softplus(a+dt_bias))
//   C_t = k_t . k_{t-1}  (per hk);  P = -g_t*C_t*beta_t;  W1 = g_t*g_{t-1}
// grid (S_), block 256 = 8 hk x 32 lanes.
// ---------------------------------------------------------------------------
__device__ __forceinline__ float gate_g(float a, float Aexp) {
    float sp = (a > 20.f) ? a : log1pf(expf(a));
    return expf(-Aexp * sp);
}

__global__ __launch_bounds__(256) void scal_kernel(const float* __restrict__ kc,
                                                   const float* __restrict__ ba,
                                                   const float* __restrict__ A_log,
                                                   const float* __restrict__ dt_bias,
                                                   float* __restrict__ scal) {
    const int t  = blockIdx.x;
    const int hk = threadIdx.x >> 5;
    const int s32 = threadIdx.x & 31;

    float c = 0.f;
    if (t > 0) {
        float4 kt = *(const float4*)&kc[((size_t)t * HK_ + hk) * DK_ + s32 * 4];
        float4 kp = *(const float4*)&kc[((size_t)(t - 1) * HK_ + hk) * DK_ + s32 * 4];
        c = kt.x * kp.x + kt.y * kp.y + kt.z * kp.z + kt.w * kp.w;
    }
    c = red32(c);

    if (s32 < 2) {
        int r = s32;
        int h = hk * 2 + r;
        float Aexp = expf(A_log[h]);
        float dtb  = dt_bias[h];
        float bv = ba[t * 32 + hk * 4 + r];
        float av = ba[t * 32 + hk * 4 + 2 + r];
        float bt = 1.f / (1.f + expf(-bv));
        float gt = gate_g(av + dtb, Aexp);
        float gp = 0.f;
        if (t > 0) {
            float ap = ba[(t - 1) * 32 + hk * 4 + 2 + r];
            gp = gate_g(ap + dtb, Aexp);
        }
        float4 o;
        o.x = -gt * c * bt;   // P
        o.y = gt * gp;        // W1
        o.z = bt;             // beta
        o.w = gt;             // g_t
        *(float4*)&scal[((size_t)h * S_ + t) * 4] = o;
    }
}

// ---------------------------------------------------------------------------
// gated delta-rule scan, lookahead form (verified R4 algebra), latency-tuned:
//   - 1 wave per block, 16 subs x 4 colgroups, 2 v-cols per thread (dual chains)
//   - pure-DPP red16 (no lgkmcnt drains in the loop)
//   - packed fp32 (v2f -> v_pk_fma_f32) for dots and state updates
//   - depth-4 slot rotation (no register copies for k_{t-1}/q_{t-1})
// grid (DV/8=16, HV=16) = 256 blocks; thread rows = sub*8..sub*8+7;
// thread cols = {v0+colg, v0+colg+4}.
// ---------------------------------------------------------------------------
__global__ __launch_bounds__(64) void scan_kernel(const float* __restrict__ qc,
                                                  const float* __restrict__ kc,
                                                  const float* __restrict__ vc,
                                                  const float* __restrict__ scal,
                                                  float* __restrict__ core) {
    const int h = blockIdx.y, v0 = blockIdx.x * 8;
    const int lane = threadIdx.x;          // 0..63
    const int sub = lane & 15, colg = lane >> 4;
    const int hk = h >> 1;

    __shared__ __align__(16) float skq[2][32][256];  // [step][ k(128) | q(128) ]
    __shared__ __align__(16) float sv[2][32][8];
    __shared__ __align__(16) float ssc[2][32][4];    // {P, W1, beta, g}

    auto stage = [&](int buf, int c) {
        const int t0 = c * 32;
        for (int j = 0; j < 32; ++j) {               // k|q: 1KB per step
            int tt = t0 + j;
            const float* src = (lane < 32)
                ? &kc[((size_t)tt * HK_ + hk) * DK_ + lane * 4]
                : &qc[((size_t)tt * HK_ + hk) * DK_ + (lane - 32) * 4];
            gl2lds16(src, &skq[buf][j][0]);
        }
#pragma unroll
        for (int i = 0; i < 4; ++i) {                // v: 8 steps x 8 cols per inst
            int tt = t0 + i * 8 + (lane >> 3);
            gl2lds4(&vc[((size_t)tt * HV_ + h) * DV_ + v0 + (lane & 7)],
                    &sv[buf][i * 8][0]);
        }
#pragma unroll
        for (int i = 0; i < 2; ++i)                  // scalars: 128 floats
            gl2lds4(&scal[((size_t)h * S_ + t0) * 4 + i * 64 + lane],
                    ((float*)&ssc[buf][0][0]) + i * 64);
    };

    v2f  S0[4] = {}, S1[4] = {};       // 8 rows x 2 cols of state
    v2f  kS[4][4] = {}, qS[4][4] = {}; // depth-4 slots
    float vS[4][2] = {};
    float4 scS[4] = {};
    float D0 = 0.f, D1 = 0.f;

    stage(0, 0);
    __syncthreads();

    auto rd = [&](int slot, int buf, int j) {
#pragma unroll
        for (int i = 0; i < 4; ++i) {
            kS[slot][i] = *(const v2f*)&skq[buf][j][sub * 8 + i * 2];
            qS[slot][i] = *(const v2f*)&skq[buf][j][128 + sub * 8 + i * 2];
        }
        vS[slot][0] = sv[buf][j][colg];
        vS[slot][1] = sv[buf][j][colg + 4];
        scS[slot] = *(const float4*)&ssc[buf][j][0];
    };

    rd(0, 0, 0);
    rd(1, 0, 1);

    for (int c = 0; c < 16; ++c) {
        const int buf = c & 1;
        if (c + 1 < 16) stage(buf ^ 1, c + 1);

#pragma unroll
        for (int j = 0; j < 32; ++j) {
            const int cur = j & 3, prv = (j + 3) & 3;
            if (j < 30) rd((j + 2) & 3, buf, j + 2);

            // U_t = k_t . S_{t-2}  (per col)
            v2f ua = kS[cur][0] * S0[0] + kS[cur][1] * S0[1]
                   + kS[cur][2] * S0[2] + kS[cur][3] * S0[3];
            v2f ub = kS[cur][0] * S1[0] + kS[cur][1] * S1[1]
                   + kS[cur][2] * S1[2] + kS[cur][3] * S1[3];
            float Ua = red16(ua.x + ua.y);
            float Ub = red16(ub.x + ub.y);

            // S_{t-2} -> S_{t-1} using k_{t-1}, g_{t-1}, D_{t-1}
            const float gp = scS[prv].w;
            const v2f gp2 = {gp, gp};
            const v2f Da2 = {D0, D0}, Db2 = {D1, D1};
#pragma unroll
            for (int i = 0; i < 4; ++i) {
                S0[i] = kS[prv][i] * Da2 + gp2 * S0[i];
                S1[i] = kS[prv][i] * Db2 + gp2 * S1[i];
            }

            // o_{t-1} = q_{t-1} . S_{t-1}
            v2f oa = qS[prv][0] * S0[0] + qS[prv][1] * S0[1]
                   + qS[prv][2] * S0[2] + qS[prv][3] * S0[3];
            v2f ob = qS[prv][0] * S1[0] + qS[prv][1] * S1[1]
                   + qS[prv][2] * S1[2] + qS[prv][3] * S1[3];
            float Oa = red16(oa.x + oa.y);
            float Ob = red16(ob.x + ob.y);
            const int tg = c * 32 + j;
            if (sub == 0 && tg > 0) {
                core[((size_t)(tg - 1) * HV_ + h) * DV_ + v0 + colg] = Oa;
                core[((size_t)(tg - 1) * HV_ + h) * DV_ + v0 + colg + 4] = Ob;
            }

            // D_t = P*D_{t-1} + (v_t - W1*U_t)*beta
            const float P = scS[cur].x, W1 = scS[cur].y, be = scS[cur].z;
            D0 = fmaf(P, D0, (vS[cur][0] - W1 * Ua) * be);
            D1 = fmaf(P, D1, (vS[cur][1] - W1 * Ub) * be);
        }
        __syncthreads();
        if (c + 1 < 16) {
            rd(0, buf ^ 1, 0);   // global steps (c+1)*32, (c+1)*32+1 -> slots 0,1
            rd(1, buf ^ 1, 1);
        }
    }

    // epilogue: S_510 -> S_511, o_511 (prv slot = 3)
    {
        const float gp = scS[3].w;
        const v2f gp2 = {gp, gp};
        const v2f Da2 = {D0, D0}, Db2 = {D1, D1};
#pragma unroll
        for (int i = 0; i < 4; ++i) {
            S0[i] = kS[3][i] * Da2 + gp2 * S0[i];
            S1[i] = kS[3][i] * Db2 + gp2 * S1[i];
        }
        v2f oa = qS[3][0] * S0[0] + qS[3][1] * S0[1]
               + qS[3][2] * S0[2] + qS[3][3] * S0[3];
        v2f ob = qS[3][0] * S1[0] + qS[3][1] * S1[1]
               + qS[3][2] * S1[2] + qS[3][3] * S1[3];
        float Oa = red16(oa.x + oa.y);
        float Ob = red16(ob.x + ob.y);
        if (sub == 0) {
            core[((size_t)(S_ - 1) * HV_ + h) * DV_ + v0 + colg] = Oa;
            core[((size_t)(S_ - 1) * HV_ + h) * DV_ + v0 + colg + 4] = Ob;
        }
    }
}

// ---------------------------------------------------------------------------
// RMS-norm + silu(z) gate -> bf16 (feeds gemm2 as A)
// ---------------------------------------------------------------------------
__global__ __launch_bounds__(128) void normgate_kernel(const float* __restrict__ core,
                                                       const float* __restrict__ qkvz,
                                                       const float* __restrict__ nw,
                                                       ushort_t* __restrict__ nh) {
    const int s  = blockIdx.x;
    const int hv = blockIdx.y;
    const int d  = threadIdx.x;

    float x = core[((size_t)s * HV_ + hv) * DV_ + d];
    float ss = x * x;
#pragma unroll
    for (int m = 1; m < 64; m <<= 1) ss += __shfl_xor(ss, m);
    __shared__ float red[2];
    int wid = threadIdx.x >> 6;
    if ((threadIdx.x & 63) == 0) red[wid] = ss;
    __syncthreads();
    float var = (red[0] + red[1]) * (1.f / 128.f);
    float rs  = rsqrtf(var + EPS_);

    float z  = qkvz[(size_t)s * QKVZ_N + (hv >> 1) * 768 + 512 + (hv & 1) * 128 + d];
    float sz = z / (1.f + expf(-z));

    float y = x * rs * nw[d] * sz;
    nh[(size_t)s * VAL_DIM_ + hv * DV_ + d] = f2bf(y);
}

// ---------------------------------------------------------------------------
// launch
// ---------------------------------------------------------------------------
extern "C" void kernel_launch(void* const* d_in, const int* in_sizes, int n_in,
                              void* d_out, int out_size, void* d_ws, size_t ws_size,
                              hipStream_t stream) {
    const float* hidden  = (const float*)d_in[0];
    const float* W_qkvz  = (const float*)d_in[1];
    const float* W_ba    = (const float*)d_in[2];
    const float* conv_w  = (const float*)d_in[3];
    const float* dt_bias = (const float*)d_in[4];
    const float* A_log   = (const float*)d_in[5];
    const float* norm_w  = (const float*)d_in[6];
    const float* W_out   = (const float*)d_in[7];
    float* out = (float*)d_out;

    char* w = (char*)d_ws;
    auto alloc = [&](size_t bytes) { char* p = w; w += (bytes + 255) & ~(size_t)255; return p; };

    float*    qkvz = (float*)alloc((size_t)S_ * QKVZ_N * 4);
    float*    ba   = (float*)alloc((size_t)S_ * 32 * 4);
    float*    qc   = (float*)alloc((size_t)S_ * KEY_DIM_ * 4);
    float*    kc   = (float*)alloc((size_t)S_ * KEY_DIM_ * 4);
    float*    vc   = (float*)alloc((size_t)S_ * VAL_DIM_ * 4);
    float*    scal = (float*)alloc((size_t)HV_ * S_ * 4 * 4);
    float*    core = (float*)alloc((size_t)S_ * VAL_DIM_ * 4);
    ushort_t* hidh = (ushort_t*)alloc((size_t)S_ * D_ * 2);
    ushort_t* nrmh = (ushort_t*)alloc((size_t)S_ * VAL_DIM_ * 2);
    ushort_t* Wqh  = (ushort_t*)alloc((size_t)D_ * QKVZ_N * 2);
    ushort_t* Woh  = (ushort_t*)alloc((size_t)VAL_DIM_ * D_ * 2);

    // 0a. hidden -> bf16
    convert_bf16<<<dim3((S_ * D_ / 4 + 255) / 256), 256, 0, stream>>>(hidden, hidh, S_ * D_ / 4);
    // 0b. W_qkvz [2048][6144] -> [6144][2048] bf16
    transpose_convert<<<dim3(QKVZ_N / 64, D_ / 64), 256, 0, stream>>>(W_qkvz, Wqh, D_, QKVZ_N);
    // 0c. W_out [2048][2048] -> [2048][2048] bf16 (transposed)
    transpose_convert<<<dim3(D_ / 64, VAL_DIM_ / 64), 256, 0, stream>>>(W_out, Woh, VAL_DIM_, D_);

    // 1. qkvz = hidden @ W_qkvz  (64x128 tiles -> 384 blocks)
    gemm_bf16<64, 128, 1, 4><<<dim3(QKVZ_N / 128, S_ / 64), 256, 0, stream>>>(
        hidh, Wqh, qkvz, S_, QKVZ_N, D_);

    // 2. ba
    ba_kernel<<<dim3(S_), 256, 0, stream>>>(hidden, W_ba, ba);

    // 3. conv + silu + l2norm
    conv_kernel<<<dim3(S_, 32), 128, 0, stream>>>(qkvz, conv_w, qc, kc, vc);

    // 4. per-step scalars {P, W1, beta, g} (gating fused)
    scal_kernel<<<dim3(S_), 256, 0, stream>>>(kc, ba, A_log, dt_bias, scal);

    // 5. scan (lookahead, dual-chain, pure-DPP reductions, packed fp32)
    scan_kernel<<<dim3(DV_ / 8, HV_), 64, 0, stream>>>(qc, kc, vc, scal, core);

    // 6. RMS norm + gate -> bf16
    normgate_kernel<<<dim3(S_, HV_), 128, 0, stream>>>(core, qkvz, norm_w, nrmh);

    // 7. out = nrm @ W_out  (64x64 tiles, 256 blocks)
    gemm_bf16<64, 64, 2, 2><<<dim3(D_ / 64, S_ / 64), 256, 0, stream>>>(
        nrmh, Woh, out, S_, D_, VAL_DIM_);
}

// Round 6
// 287.098 us; speedup vs baseline: 1.0420x; 1.0420x over previous
//
#include <hip/hip_runtime.h>
#include <hip/hip_bf16.h>
#include <math.h>

// Problem constants
#define S_  512
#define D_  2048
#define HK_ 8
#define HV_ 16
#define DK_ 128
#define DV_ 128
#define KEY_DIM_ 1024
#define VAL_DIM_ 2048
#define QKVZ_N  6144
#define EPS_ 1e-6f
#define SPAD_ (S_ + 8)   // padded step count for lookahead overreads

typedef __attribute__((ext_vector_type(8))) short short8;
typedef __attribute__((ext_vector_type(4))) float f32x4;
typedef __attribute__((ext_vector_type(2))) float v2f;
typedef unsigned short ushort_t;
typedef unsigned int uint_t;

// ---------------------------------------------------------------------------
// helpers
// ---------------------------------------------------------------------------
__device__ __forceinline__ ushort_t f2bf(float x) {
    uint_t u = __float_as_uint(x);
    return (ushort_t)((u + 0x7FFFu + ((u >> 16) & 1u)) >> 16);
}

__device__ __forceinline__ void gl2lds16(const void* g, void* l) {
    __builtin_amdgcn_global_load_lds((const __attribute__((address_space(1))) uint_t*)g,
                                     (__attribute__((address_space(3))) uint_t*)l, 16, 0, 0);
}
__device__ __forceinline__ void gl2lds4(const void* g, void* l) {
    __builtin_amdgcn_global_load_lds((const __attribute__((address_space(1))) uint_t*)g,
                                     (__attribute__((address_space(3))) uint_t*)l, 4, 0, 0);
}

// ---------------------------------------------------------------------------
// fp32 -> bf16 (flat)
// ---------------------------------------------------------------------------
__global__ __launch_bounds__(256) void convert_bf16(const float* __restrict__ X,
                                                    ushort_t* __restrict__ H, int n4) {
    int i = blockIdx.x * blockDim.x + threadIdx.x;
    if (i >= n4) return;
    float4 v = ((const float4*)X)[i];
    ushort4 h;
    h.x = f2bf(v.x); h.y = f2bf(v.y); h.z = f2bf(v.z); h.w = f2bf(v.w);
    ((ushort4*)H)[i] = h;
}

// ---------------------------------------------------------------------------
// W[K][N] fp32 -> T[N][K] bf16 (transpose + convert); grid (N/64, K/64), 256 thr
// ---------------------------------------------------------------------------
__global__ __launch_bounds__(256) void transpose_convert(const float* __restrict__ W,
                                                         ushort_t* __restrict__ Th,
                                                         int K, int N) {
    __shared__ float tile[64][65];
    const int kb = blockIdx.y * 64, nb = blockIdx.x * 64;
    const int t = threadIdx.x;
#pragma unroll
    for (int i = 0; i < 4; ++i) {
        int r = (t >> 4) + i * 16;
        int c4 = (t & 15) * 4;
        float4 v = *(const float4*)&W[(size_t)(kb + r) * N + nb + c4];
        tile[r][c4 + 0] = v.x; tile[r][c4 + 1] = v.y;
        tile[r][c4 + 2] = v.z; tile[r][c4 + 3] = v.w;
    }
    __syncthreads();
#pragma unroll
    for (int i = 0; i < 4; ++i) {
        int idx = t + 256 * i;
        int n = idx >> 4;
        int k4 = (idx & 15) * 4;
        ushort4 h;
        h.x = f2bf(tile[k4 + 0][n]); h.y = f2bf(tile[k4 + 1][n]);
        h.z = f2bf(tile[k4 + 2][n]); h.w = f2bf(tile[k4 + 3][n]);
        *(ushort4*)&Th[(size_t)(nb + n) * K + kb + k4] = h;
    }
}

// ---------------------------------------------------------------------------
// bf16 MFMA GEMM, m97 structure (unchanged from R5)
// ---------------------------------------------------------------------------
template<int BM, int BN, int WR, int WC>
__global__ __launch_bounds__(256) void gemm_bf16(const ushort_t* __restrict__ A,
                                                 const ushort_t* __restrict__ B,
                                                 float* __restrict__ C,
                                                 int M, int N, int K) {
    constexpr int TM = BM / (16 * WR);
    constexpr int TN = BN / (16 * WC);
    constexpr int AI = (BM / 16) * 2;
    constexpr int BI = (BN / 16) * 2;

    __shared__ __align__(16) ushort_t sA[2][2][BM][32];
    __shared__ __align__(16) ushort_t sB[2][2][BN][32];

    const int t = threadIdx.x;
    const int w = t >> 6, lane = t & 63;
    const int wr = w / WC, wc = w % WC;
    const int lm = lane & 15, quad = lane >> 4;
    const int m0 = blockIdx.y * BM, n0 = blockIdx.x * BN;
    const int lrow = lane >> 2;
    const int lch  = (lane & 3) * 8;

    auto stage = [&](int buf, int k0) {
#pragma unroll
        for (int j = w; j < AI; j += 4) {
            int ks = j & 1, r0 = (j >> 1) * 16;
            gl2lds16(&A[(size_t)(m0 + r0 + lrow) * K + k0 + ks * 32 + lch],
                     &sA[buf][ks][r0][0]);
        }
#pragma unroll
        for (int j = w; j < BI; j += 4) {
            int ks = j & 1, r0 = (j >> 1) * 16;
            gl2lds16(&B[(size_t)(n0 + r0 + lrow) * K + k0 + ks * 32 + lch],
                     &sB[buf][ks][r0][0]);
        }
    };

    f32x4 acc[TM][TN] = {};
    stage(0, 0);
    __syncthreads();

    const int NK = K / 64;
    for (int it = 0; it < NK; ++it) {
        int buf = it & 1;
        if (it + 1 < NK) stage(buf ^ 1, (it + 1) * 64);
#pragma unroll
        for (int ks = 0; ks < 2; ++ks) {
            short8 bf[TN];
#pragma unroll
            for (int ni = 0; ni < TN; ++ni)
                bf[ni] = *(const short8*)&sB[buf][ks][wc * (TN * 16) + ni * 16 + lm][quad * 8];
#pragma unroll
            for (int mi = 0; mi < TM; ++mi) {
                short8 af = *(const short8*)&sA[buf][ks][wr * (TM * 16) + mi * 16 + lm][quad * 8];
#pragma unroll
                for (int ni = 0; ni < TN; ++ni)
                    acc[mi][ni] = __builtin_amdgcn_mfma_f32_16x16x32_bf16(af, bf[ni], acc[mi][ni], 0, 0, 0);
            }
        }
        __syncthreads();
    }

#pragma unroll
    for (int mi = 0; mi < TM; ++mi)
#pragma unroll
        for (int ni = 0; ni < TN; ++ni) {
            int row = m0 + wr * TM * 16 + mi * 16 + quad * 4;
            int col = n0 + wc * TN * 16 + ni * 16 + lm;
#pragma unroll
            for (int r = 0; r < 4; ++r)
                C[(size_t)(row + r) * N + col] = acc[mi][ni][r];
        }
}

// ---------------------------------------------------------------------------
// ba = hidden @ W_ba  (512x2048 @ 2048x32)
// ---------------------------------------------------------------------------
__global__ __launch_bounds__(256) void ba_kernel(const float* __restrict__ hid,
                                                 const float* __restrict__ Wba,
                                                 float* __restrict__ ba) {
    const int s = blockIdx.x;
    const int j = threadIdx.x & 31;
    const int kg = threadIdx.x >> 5;
    const float* h = hid + (size_t)s * D_;
    float sum = 0.f;
    const int k0 = kg * 256;
#pragma unroll 8
    for (int k = k0; k < k0 + 256; ++k)
        sum = fmaf(h[k], Wba[(size_t)k * 32 + j], sum);
    __shared__ float red[8][32];
    red[kg][j] = sum;
    __syncthreads();
    if (threadIdx.x < 32) {
        float tot = 0.f;
#pragma unroll
        for (int r = 0; r < 8; ++r) tot += red[r][j];
        ba[s * 32 + j] = tot;
    }
}

// ---------------------------------------------------------------------------
// causal depthwise conv (K=4) + silu + l2norm (q/k). grid (S,32), block 128.
// ---------------------------------------------------------------------------
__global__ __launch_bounds__(128) void conv_kernel(const float* __restrict__ qkvz,
                                                   const float* __restrict__ conv_w,
                                                   float* __restrict__ qc,
                                                   float* __restrict__ kc,
                                                   float* __restrict__ vc) {
    const int s   = blockIdx.x;
    const int grp = blockIdx.y;
    const int d   = threadIdx.x;

    int col, c;
    if (grp < 8) {
        int hk = grp;
        col = hk * 768 + d;
        c   = hk * 128 + d;
    } else if (grp < 16) {
        int hk = grp - 8;
        col = hk * 768 + 128 + d;
        c   = 1024 + (hk * 128 + d);
    } else {
        int hv = grp - 16;
        col = (hv >> 1) * 768 + 256 + (hv & 1) * 128 + d;
        c   = 2048 + (hv * 128 + d);
    }

    const float w0 = conv_w[c * 4 + 0];
    const float w1 = conv_w[c * 4 + 1];
    const float w2 = conv_w[c * 4 + 2];
    const float w3 = conv_w[c * 4 + 3];

    float x = 0.f;
    if (s - 3 >= 0) x += qkvz[(size_t)(s - 3) * QKVZ_N + col] * w0;
    if (s - 2 >= 0) x += qkvz[(size_t)(s - 2) * QKVZ_N + col] * w1;
    if (s - 1 >= 0) x += qkvz[(size_t)(s - 1) * QKVZ_N + col] * w2;
    x += qkvz[(size_t)s * QKVZ_N + col] * w3;

    x = x / (1.f + expf(-x));

    if (grp < 16) {
        float ss = x * x;
#pragma unroll
        for (int m = 1; m < 64; m <<= 1) ss += __shfl_xor(ss, m);
        __shared__ float red[2];
        int wid = threadIdx.x >> 6;
        if ((threadIdx.x & 63) == 0) red[wid] = ss;
        __syncthreads();
        float tot = red[0] + red[1];
        float scale = rsqrtf(tot + EPS_);
        if (grp < 8) {
            x = x * scale * 0.08838834764831845f;   // * DK^-0.5
            qc[((size_t)s * HK_ + grp) * DK_ + d] = x;
        } else {
            x = x * scale;
            kc[((size_t)s * HK_ + (grp - 8)) * DK_ + d] = x;
        }
    } else {
        vc[((size_t)s * HV_ + (grp - 16)) * DV_ + d] = x;
    }
}

// ---------------------------------------------------------------------------
// cross-lane reductions
// ---------------------------------------------------------------------------
template<int CTRL>
__device__ __forceinline__ float dpp_xor(float x) {
    int v = __builtin_amdgcn_update_dpp(0, __float_as_int(x), CTRL, 0xF, 0xF, true);
    return __int_as_float(v);
}
__device__ __forceinline__ float red16(float x) {
    x += dpp_xor<0xB1>(x);   // xor 1
    x += dpp_xor<0x4E>(x);   // xor 2
    x += dpp_xor<0x141>(x);  // xor 4 (row_half_mirror)
    x += dpp_xor<0x140>(x);  // xor 8 (row_mirror)
    return x;
}
__device__ __forceinline__ float red32(float x) {
    x = red16(x);
    x += __int_as_float(__builtin_amdgcn_ds_swizzle(__float_as_int(x), 0x401F)); // xor 16
    return x;
}

__device__ __forceinline__ float gate_g(float a, float Aexp) {
    float sp = (a > 20.f) ? a : log1pf(expf(a));
    return expf(-Aexp * sp);
}

// ---------------------------------------------------------------------------
// scal_kernel: per (t,h) the J=4 lookahead scalars.
//   c_j = k_t.k_{t-j} (j=1..3), d_j = q_t.k_{t-j} (j=0..3)   [0 if t-j<0]
//   layout [h][SPAD][16]: [0..3]=(g,beta,G4,0) [4..7]=(a1,a2,a3,bU) [8..11]=(w0..w3)
//   a_j = -beta*Gj*c_j ; bU = -beta*G4 ; w_j = G_{j}*d_j ; G4 = g_t..g_{t-3}
// grid (S_), block 256 = 8 hk x 32 lanes.
// ---------------------------------------------------------------------------
__global__ __launch_bounds__(256) void scal_kernel(const float* __restrict__ kc,
                                                   const float* __restrict__ qc,
                                                   const float* __restrict__ ba,
                                                   const float* __restrict__ A_log,
                                                   const float* __restrict__ dt_bias,
                                                   float* __restrict__ scal) {
    const int t  = blockIdx.x;
    const int hk = threadIdx.x >> 5;
    const int l  = threadIdx.x & 31;

    const float* kt = &kc[((size_t)t * HK_ + hk) * DK_ + l * 4];
    const float* qt = &qc[((size_t)t * HK_ + hk) * DK_ + l * 4];
    const float4 zz = {0.f, 0.f, 0.f, 0.f};
    float4 k0 = *(const float4*)kt;
    float4 q0 = *(const float4*)qt;
    float4 k1 = (t >= 1) ? *(const float4*)(kt - (size_t)HK_ * DK_)     : zz;
    float4 k2 = (t >= 2) ? *(const float4*)(kt - (size_t)2 * HK_ * DK_) : zz;
    float4 k3 = (t >= 3) ? *(const float4*)(kt - (size_t)3 * HK_ * DK_) : zz;

    auto dot4 = [](float4 a, float4 b) { return a.x*b.x + a.y*b.y + a.z*b.z + a.w*b.w; };
    float c1 = red32(dot4(k0, k1));
    float c2 = red32(dot4(k0, k2));
    float c3 = red32(dot4(k0, k3));
    float d0 = red32(dot4(q0, k0));
    float d1 = red32(dot4(q0, k1));
    float d2 = red32(dot4(q0, k2));
    float d3 = red32(dot4(q0, k3));

    if (l < 2) {
        int h = hk * 2 + l;
        float Aexp = expf(A_log[h]);
        float dtb  = dt_bias[h];
        float bv = ba[t * 32 + hk * 4 + l];
        float av = ba[t * 32 + hk * 4 + 2 + l];
        float be = 1.f / (1.f + expf(-bv));
        float g0 = gate_g(av + dtb, Aexp);
        float g1 = 1.f, g2 = 1.f, g3 = 1.f;
        if (t >= 1) g1 = gate_g(ba[(t - 1) * 32 + hk * 4 + 2 + l] + dtb, Aexp);
        if (t >= 2) g2 = gate_g(ba[(t - 2) * 32 + hk * 4 + 2 + l] + dtb, Aexp);
        if (t >= 3) g3 = gate_g(ba[(t - 3) * 32 + hk * 4 + 2 + l] + dtb, Aexp);
        float G2 = g0 * g1, G3 = G2 * g2, G4 = G3 * g3;
        float4 oC = {g0, be, G4, 0.f};
        float4 oA = {-be * g0 * c1, -be * G2 * c2, -be * G3 * c3, -be * G4};
        float4 oB = {d0, g0 * d1, G2 * d2, G3 * d3};
        float* dst = &scal[(size_t)(h * SPAD_ + t) * 16];
        *(float4*)&dst[0]  = oC;
        *(float4*)&dst[4]  = oA;
        *(float4*)&dst[8]  = oB;
        *(float4*)&dst[12] = zz;
    }
}

// ---------------------------------------------------------------------------
// gated delta-rule scan, J=4 lookahead (exact algebra; reductions off the chain):
//   U_t = k_t.S_{t-4}, V_t = q_t.S_{t-4}  (dots started 2 iters early)
//   delta_t = beta v_t + bU*U_t + a3 d_{t-3} + a2 d_{t-2} + a1 d_{t-1}   (chain = 1 fma)
//   o_t = G4*V_t + w0 d_t + w1 d_{t-1} + w2 d_{t-2} + w3 d_{t-3}
//   S advanced lazily (applies step t-2 at iter t)
// grid (DV/8=16, HV=16) = 256 blocks; block = 128 thr (2 waves, 4 cols each);
// thread = 1 col, 16 subs x 8 rows; red16 pure-DPP, 2-iter slack.
// ---------------------------------------------------------------------------
__global__ __launch_bounds__(128) void scan_kernel(const float* __restrict__ qc,
                                                   const float* __restrict__ kc,
                                                   const float* __restrict__ vc,
                                                   const float* __restrict__ scal,
                                                   float* __restrict__ core) {
    const int h = blockIdx.y, v0 = blockIdx.x * 8;
    const int tid = threadIdx.x;
    const int w = tid >> 6, lane = tid & 63;
    const int sub = lane & 15, colg = lane >> 4;
    const int vloc = w * 4 + colg;
    const int v = v0 + vloc;
    const int hk = h >> 1;

    __shared__ __align__(16) float skq[2][32][256];  // [step][k(128)|q(128)]
    __shared__ __align__(16) float sv[2][32][8];
    __shared__ __align__(16) float ssc[2][32][16];
    __shared__ __align__(16) float hkq[2][4][256];   // head: first 4 steps of a chunk
    __shared__ __align__(16) float hv[2][4][8];
    __shared__ __align__(16) float hsc[2][4][16];

    auto stage_chunk = [&](int buf, int c) {
        const int t0 = c * 32;
        for (int j = w * 16; j < w * 16 + 16; ++j) {
            int tt = t0 + j;
            const float* src = (lane < 32)
                ? &kc[((size_t)tt * HK_ + hk) * DK_ + lane * 4]
                : &qc[((size_t)tt * HK_ + hk) * DK_ + (lane - 32) * 4];
            gl2lds16(src, &skq[buf][j][0]);
        }
        if (w == 0) {
#pragma unroll
            for (int i = 0; i < 4; ++i) {
                int tt = t0 + i * 8 + (lane >> 3);
                gl2lds4(&vc[((size_t)tt * HV_ + h) * DV_ + v0 + (lane & 7)],
                        &sv[buf][i * 8][0]);
            }
        } else {
#pragma unroll
            for (int i = 0; i < 2; ++i)
                gl2lds16(&scal[(size_t)(h * SPAD_ + t0) * 16 + i * 256 + lane * 4],
                         &ssc[buf][i * 16][0]);
        }
    };
    auto stage_head = [&](int c) {   // head slot for chunk c = c&1
        const int hb = c & 1;
        const int t0 = c * 32;
        if (w == 1) {
#pragma unroll
            for (int j = 0; j < 4; ++j) {
                int tt = t0 + j;
                const float* src = (lane < 32)
                    ? &kc[((size_t)tt * HK_ + hk) * DK_ + lane * 4]
                    : &qc[((size_t)tt * HK_ + hk) * DK_ + (lane - 32) * 4];
                gl2lds16(src, &hkq[hb][j][0]);
            }
        } else {
            if (lane < 32)
                gl2lds4(&vc[((size_t)(t0 + (lane >> 3)) * HV_ + h) * DV_ + v0 + (lane & 7)],
                        &hv[hb][0][0]);
            if (lane < 16)
                gl2lds16(&scal[(size_t)(h * SPAD_ + t0) * 16 + lane * 4],
                         &hsc[hb][0][0]);
        }
    };

    // pipeline registers (all slot indices compile-time after unroll)
    v2f Sr[4] = {};                       // 8 rows x 1 col of 4-stale state
    v2f kR[8][4] = {};                    // k slots, step&7 (lifetime 6)
    v2f qR[4][4] = {};                    // q slots, step&3
    float vR[4] = {};
    float4 scA[4] = {}, scB[4] = {}, scC[4] = {};
    float U[4] = {}, V[4] = {}, dl[4] = {};

    stage_chunk(0, 0);
    stage_head(1);
    __syncthreads();

    // prologue: kq for steps 0..3, scal/v for steps 0,1.
    // slots for steps -2,-1 (kR[6],kR[7], scC[2].x, dl[2], dl[3]) stay zero ->
    // the first two lazy S-updates are no-ops and U_0..U_3 = 0 (S_{-4..-1}=0).
#pragma unroll
    for (int p = 0; p < 4; ++p)
#pragma unroll
        for (int i = 0; i < 4; ++i) {
            kR[p][i] = *(const v2f*)&skq[0][p][sub * 8 + i * 2];
            qR[p][i] = *(const v2f*)&skq[0][p][128 + sub * 8 + i * 2];
        }
#pragma unroll
    for (int p = 0; p < 2; ++p) {
        scC[p] = *(const float4*)&ssc[0][p][0];
        scA[p] = *(const float4*)&ssc[0][p][4];
        scB[p] = *(const float4*)&ssc[0][p][8];
        vR[p] = sv[0][p][vloc];
    }

    for (int c = 0; c < 16; ++c) {
        const int buf = c & 1;
        const int hb = (c + 1) & 1;      // head data for chunk c+1 (staged at c-1)
        if (c + 1 < 16) stage_chunk(buf ^ 1, c + 1);
        if (c + 2 < 16) stage_head(c + 2);
        const int t0 = c * 32;

#pragma unroll
        for (int j = 0; j < 32; ++j) {
            // 1. lazy S-update: apply step j-2 (g, k, delta from slots; zeros at start)
            {
                const float g  = ((const float*)&scC[(j + 2) & 3])[0];
                const float dd = dl[(j + 2) & 3];
                const v2f g2 = {g, g}, dd2 = {dd, dd};
#pragma unroll
                for (int i = 0; i < 4; ++i)
                    Sr[i] = kR[(j + 6) & 7][i] * dd2 + g2 * Sr[i];
            }
            // 2. prefetch k/q for step j+4 (head region for j>=28)
            {
                const float* kb = (j < 28) ? &skq[buf][j + 4][0] : &hkq[hb][j - 28][0];
#pragma unroll
                for (int i = 0; i < 4; ++i) {
                    kR[(j + 4) & 7][i] = *(const v2f*)&kb[sub * 8 + i * 2];
                    qR[(j + 4) & 3][i] = *(const v2f*)&kb[128 + sub * 8 + i * 2];
                }
            }
            // 3. prefetch scal/v for step j+2 (head region for j>=30)
            {
                const float* sb = (j < 30) ? &ssc[buf][j + 2][0] : &hsc[hb][j - 30][0];
                scC[(j + 2) & 3] = *(const float4*)&sb[0];
                scA[(j + 2) & 3] = *(const float4*)&sb[4];
                scB[(j + 2) & 3] = *(const float4*)&sb[8];
                const float* vb = (j < 30) ? &sv[buf][j + 2][0] : &hv[hb][j - 30][0];
                vR[(j + 2) & 3] = vb[vloc];
            }
            // 4. dots for step j+2 vs Sr (= S_{t0+j-2}); reduction has 2 iters of slack
            {
                v2f ua = kR[(j + 2) & 7][0] * Sr[0] + kR[(j + 2) & 7][1] * Sr[1]
                       + kR[(j + 2) & 7][2] * Sr[2] + kR[(j + 2) & 7][3] * Sr[3];
                v2f va = qR[(j + 2) & 3][0] * Sr[0] + qR[(j + 2) & 3][1] * Sr[1]
                       + qR[(j + 2) & 3][2] * Sr[2] + qR[(j + 2) & 3][3] * Sr[3];
                U[(j + 2) & 3] = red16(ua.x + ua.y);
                V[(j + 2) & 3] = red16(va.x + va.y);
            }
            // 5. delta_j (1-fma chain) and o_j
            {
                const float4 A = scA[j & 3], B = scB[j & 3], Cc = scC[j & 3];
                const float d1 = dl[(j + 3) & 3], d2 = dl[(j + 2) & 3], d3 = dl[(j + 1) & 3];
                const float E = fmaf(A.w, U[j & 3], Cc.y * vR[j & 3]);
                const float X = fmaf(A.y, d2, fmaf(A.z, d3, E));
                const float dn = fmaf(A.x, d1, X);
                const float o = fmaf(B.x, dn, fmaf(B.y, d1,
                                  fmaf(B.z, d2, fmaf(B.w, d3, Cc.z * V[j & 3]))));
                if (sub == 0)
                    core[((size_t)(t0 + j) * HV_ + h) * DV_ + v] = o;
                dl[j & 3] = dn;
            }
        }
        __syncthreads();
    }
}

// ---------------------------------------------------------------------------
// RMS-norm + silu(z) gate -> bf16 (feeds gemm2 as A)
// ---------------------------------------------------------------------------
__global__ __launch_bounds__(128) void normgate_kernel(const float* __restrict__ core,
                                                       const float* __restrict__ qkvz,
                                                       const float* __restrict__ nw,
                                                       ushort_t* __restrict__ nh) {
    const int s  = blockIdx.x;
    const int hv = blockIdx.y;
    const int d  = threadIdx.x;

    float x = core[((size_t)s * HV_ + hv) * DV_ + d];
    float ss = x * x;
#pragma unroll
    for (int m = 1; m < 64; m <<= 1) ss += __shfl_xor(ss, m);
    __shared__ float red[2];
    int wid = threadIdx.x >> 6;
    if ((threadIdx.x & 63) == 0) red[wid] = ss;
    __syncthreads();
    float var = (red[0] + red[1]) * (1.f / 128.f);
    float rs  = rsqrtf(var + EPS_);

    float z  = qkvz[(size_t)s * QKVZ_N + (hv >> 1) * 768 + 512 + (hv & 1) * 128 + d];
    float sz = z / (1.f + expf(-z));

    float y = x * rs * nw[d] * sz;
    nh[(size_t)s * VAL_DIM_ + hv * DV_ + d] = f2bf(y);
}

// ---------------------------------------------------------------------------
// launch
// ---------------------------------------------------------------------------
extern "C" void kernel_launch(void* const* d_in, const int* in_sizes, int n_in,
                              void* d_out, int out_size, void* d_ws, size_t ws_size,
                              hipStream_t stream) {
    const float* hidden  = (const float*)d_in[0];
    const float* W_qkvz  = (const float*)d_in[1];
    const float* W_ba    = (const float*)d_in[2];
    const float* conv_w  = (const float*)d_in[3];
    const float* dt_bias = (const float*)d_in[4];
    const float* A_log   = (const float*)d_in[5];
    const float* norm_w  = (const float*)d_in[6];
    const float* W_out   = (const float*)d_in[7];
    float* out = (float*)d_out;

    char* w = (char*)d_ws;
    auto alloc = [&](size_t bytes) { char* p = w; w += (bytes + 255) & ~(size_t)255; return p; };

    float*    qkvz = (float*)alloc((size_t)S_ * QKVZ_N * 4);
    float*    ba   = (float*)alloc((size_t)S_ * 32 * 4);
    float*    qc   = (float*)alloc((size_t)SPAD_ * KEY_DIM_ * 4);   // padded (lookahead reads)
    float*    kc   = (float*)alloc((size_t)SPAD_ * KEY_DIM_ * 4);
    float*    vc   = (float*)alloc((size_t)SPAD_ * VAL_DIM_ * 4);
    float*    scal = (float*)alloc((size_t)HV_ * SPAD_ * 16 * 4);
    float*    core = (float*)alloc((size_t)S_ * VAL_DIM_ * 4);
    ushort_t* hidh = (ushort_t*)alloc((size_t)S_ * D_ * 2);
    ushort_t* nrmh = (ushort_t*)alloc((size_t)S_ * VAL_DIM_ * 2);
    ushort_t* Wqh  = (ushort_t*)alloc((size_t)D_ * QKVZ_N * 2);
    ushort_t* Woh  = (ushort_t*)alloc((size_t)VAL_DIM_ * D_ * 2);

    // 0a. hidden -> bf16
    convert_bf16<<<dim3((S_ * D_ / 4 + 255) / 256), 256, 0, stream>>>(hidden, hidh, S_ * D_ / 4);
    // 0b. W_qkvz -> [6144][2048] bf16
    transpose_convert<<<dim3(QKVZ_N / 64, D_ / 64), 256, 0, stream>>>(W_qkvz, Wqh, D_, QKVZ_N);
    // 0c. W_out -> [2048][2048] bf16 (transposed)
    transpose_convert<<<dim3(D_ / 64, VAL_DIM_ / 64), 256, 0, stream>>>(W_out, Woh, VAL_DIM_, D_);

    // 1. qkvz = hidden @ W_qkvz
    gemm_bf16<64, 128, 1, 4><<<dim3(QKVZ_N / 128, S_ / 64), 256, 0, stream>>>(
        hidh, Wqh, qkvz, S_, QKVZ_N, D_);

    // 2. ba
    ba_kernel<<<dim3(S_), 256, 0, stream>>>(hidden, W_ba, ba);

    // 3. conv + silu + l2norm
    conv_kernel<<<dim3(S_, 32), 128, 0, stream>>>(qkvz, conv_w, qc, kc, vc);

    // 4. lookahead scalars (gating fused)
    scal_kernel<<<dim3(S_), 256, 0, stream>>>(kc, qc, ba, A_log, dt_bias, scal);

    // 5. scan (J=4 lookahead; reductions off the serial chain)
    scan_kernel<<<dim3(DV_ / 8, HV_), 128, 0, stream>>>(qc, kc, vc, scal, core);

    // 6. RMS norm + gate -> bf16
    normgate_kernel<<<dim3(S_, HV_), 128, 0, stream>>>(core, qkvz, norm_w, nrmh);

    // 7. out = nrm @ W_out
    gemm_bf16<64, 64, 2, 2><<<dim3(D_ / 64, S_ / 64), 256, 0, stream>>>(
        nrmh, Woh, out, S_, D_, VAL_DIM_);
}